// Round 6
// baseline (998.071 us; speedup 1.0000x reference)
//
#include <hip/hip_runtime.h>

#define D 64
#define NB 256      // partition blocks for hist/scatter
#define BSHIFT 7    // bucket = 128 nodes
#define BUCK (1 << BSHIFT)
#define APAD 65     // acc row stride: 65%32==1 -> bank=(dloc+8p+k)%32, spread

typedef unsigned int u32;
typedef unsigned short u16;
typedef short bf8v __attribute__((ext_vector_type(8)));
typedef float f4v __attribute__((ext_vector_type(4)));

__device__ __forceinline__ float bf_lo(u32 p) { return __uint_as_float(p << 16); }
__device__ __forceinline__ float bf_hi(u32 p) { return __uint_as_float(p & 0xffff0000u); }
__device__ __forceinline__ u32 bf_rne(float f) {
    u32 u = __float_as_uint(f);
    return (u + 0x7fffu + ((u >> 16) & 1u)) >> 16;
}

// ---------------- pass A: per-block bucket histogram (LDS atomics only) --------
__global__ __launch_bounds__(256) void hist_k(const int* __restrict__ dst,
                                              int* __restrict__ histT, int E, int chunk,
                                              int nbuck, int* __restrict__ donecnt) {
    __shared__ int hh[1024];
    int t = threadIdx.x;
    if (blockIdx.x == 0 && t == 0) *donecnt = 0;
    for (int b = t; b < nbuck; b += 256) hh[b] = 0;
    __syncthreads();
    int start = blockIdx.x * chunk;
    int endi = min(E, start + chunk);
    for (int j = start + t; j < endi; j += 256) atomicAdd(&hh[dst[j] >> BSHIFT], 1);
    __syncthreads();
    for (int b = t; b < nbuck; b += 256) histT[b * NB + blockIdx.x] = hh[b];
}

// ---------------- grid scan for histT, final partial-scan folded in ----------
// Last block to finish (device atomic) scans the <=256 partials into blockoff.
__global__ __launch_bounds__(1024) void gscan1_k(const int* __restrict__ in,
                                                 int* __restrict__ out,
                                                 int* __restrict__ partials,
                                                 int* __restrict__ blockoff,
                                                 int* __restrict__ donecnt, int M) {
    __shared__ int wsum[16];
    __shared__ int ps[256];
    __shared__ int lastflag;
    int t = threadIdx.x, wave = t >> 6, lane = t & 63;
    int i = blockIdx.x * 1024 + t;
    int v = (i < M) ? in[i] : 0;
    int x = v;
#pragma unroll
    for (int off = 1; off < 64; off <<= 1) {
        int y = __shfl_up(x, off, 64);
        if (lane >= off) x += y;
    }
    if (lane == 63) wsum[wave] = x;
    __syncthreads();
    if (wave == 0) {
        int s = (lane < 16) ? wsum[lane] : 0;
#pragma unroll
        for (int off = 1; off < 16; off <<= 1) {
            int y = __shfl_up(s, off, 64);
            if (lane >= off) s += y;
        }
        if (lane < 16) wsum[lane] = s;
    }
    __syncthreads();
    int woff = (wave > 0) ? wsum[wave - 1] : 0;
    if (i < M) out[i] = x + woff - v;
    if (t == 0) {
        partials[blockIdx.x] = wsum[15];
        __threadfence();  // release partials before signaling
        int prev = atomicAdd(donecnt, 1);
        lastflag = (prev == (int)gridDim.x - 1);
    }
    __syncthreads();
    if (lastflag) {  // block-uniform branch: barriers inside are legal
        int nb = gridDim.x;
        if (t < 256) ps[t] = (t < nb) ? partials[t] : 0;
        __syncthreads();
        for (int off = 1; off < 256; off <<= 1) {
            int add = (t < 256 && t >= off) ? ps[t - off] : 0;
            __syncthreads();
            if (t < 256) ps[t] += add;
            __syncthreads();
        }
        if (t < 256) blockoff[t] = ps[t] - ((t < nb) ? partials[t] : 0);
    }
}

// seg(x) = histT[x] + blockoff2[x>>10]
__device__ __forceinline__ int seg_at(const int* __restrict__ histT,
                                      const int* __restrict__ blockoff2, int x) {
    return histT[x] + blockoff2[x >> 10];
}

// ---------------- pass B: scatter edges into bucket-sorted segments ----------
// Packed 4B entries: src in bits 0..23, dst&127 in bits 24..31.
__global__ __launch_bounds__(256) void bscat_k(const int* __restrict__ src,
                                               const int* __restrict__ dst,
                                               const int* __restrict__ histT,
                                               const int* __restrict__ blockoff2,
                                               u32* __restrict__ pairs, int E, int chunk,
                                               int nbuck) {
    __shared__ int sbase[1024];
    __shared__ int rank[1024];
    int t = threadIdx.x;
    for (int b = t; b < nbuck; b += 256) {
        sbase[b] = seg_at(histT, blockoff2, b * NB + blockIdx.x);
        rank[b] = 0;
    }
    __syncthreads();
    int start = blockIdx.x * chunk;
    int endi = min(E, start + chunk);
    for (int j = start + t; j < endi; j += 256) {
        int d = dst[j];
        int b = d >> BSHIFT;
        int pos = sbase[b] + atomicAdd(&rank[b], 1);
        pairs[pos] = (u32)src[j] | ((u32)(d & (BUCK - 1)) << 24);
    }
}

__device__ __forceinline__ void load_B(const float* __restrict__ W, bf8v Bf[2][4], int m,
                                       int quad) {
#pragma unroll
    for (int kc = 0; kc < 2; ++kc)
#pragma unroll
        for (int nb = 0; nb < 4; ++nb)
#pragma unroll
            for (int j = 0; j < 8; ++j)
                Bf[kc][nb][j] = (short)bf_rne(W[(32 * kc + 8 * quad + j) * D + m + 16 * nb]);
}

// ---------------- pass C: per-node degree (LDS) -> dinv, FUSED layer-1 GEMM ---
// Phase 1: count this bucket's 128 nodes from its pairs segment; dinv to LDS +
// global. Phase 2 (same block, dinv LDS-hot): h' = bf16(dinv[row] * (x @ W1))
// for the same 128 rows. Folding dinv into the GEMM epilogue makes both agg
// passes weight-free: out[d] = relu(dinv[d]*(h'[d] + sum h'[src]) + b).
__global__ __launch_bounds__(256) void bcount_gemm_k(
    const u32* __restrict__ pairs, const int* __restrict__ histT,
    const int* __restrict__ blockoff2, float* __restrict__ dinv,
    const float* __restrict__ xf, const float* __restrict__ W,
    u16* __restrict__ hout, int N, int nbuck, int E) {
    __shared__ int c[BUCK];
    __shared__ float ldv[BUCK];
    int t = threadIdx.x;
    int b = blockIdx.x;
    int base = b << BSHIFT;
    if (t < BUCK) c[t] = 0;
    __syncthreads();
    int s0 = seg_at(histT, blockoff2, b * NB);
    int s1 = (b + 1 < nbuck) ? seg_at(histT, blockoff2, (b + 1) * NB) : E;
    for (int j = s0 + t; j < s1; j += 256) atomicAdd(&c[pairs[j] >> 24], 1);
    __syncthreads();
    if (t < BUCK && base + t < N) {
        float di = rsqrtf((float)c[t] + 1.0f);
        ldv[t] = di;
        dinv[base + t] = di;
    }
    __syncthreads();
    // layer-1 gemm, rows [base, base+128), scaled store
    int wave = t >> 6, lane = t & 63, m = lane & 15, quad = lane >> 4;
    bf8v Bf[2][4];
    load_B(W, Bf, m, quad);
    for (int g = wave; g < BUCK / 16; g += 4) {
        int gbase = base + g * 16;
        if (gbase >= N) break;
        int r0 = gbase + m;
        if (r0 >= N) r0 = N - 1;
        const float* rp = xf + (size_t)r0 * D;
        float4 a0 = *(const float4*)(rp + quad * 8);
        float4 a1 = *(const float4*)(rp + quad * 8 + 4);
        float4 a2 = *(const float4*)(rp + 32 + quad * 8);
        float4 a3 = *(const float4*)(rp + 32 + quad * 8 + 4);
        bf8v Af0, Af1;
        Af0[0] = (short)bf_rne(a0.x); Af0[1] = (short)bf_rne(a0.y);
        Af0[2] = (short)bf_rne(a0.z); Af0[3] = (short)bf_rne(a0.w);
        Af0[4] = (short)bf_rne(a1.x); Af0[5] = (short)bf_rne(a1.y);
        Af0[6] = (short)bf_rne(a1.z); Af0[7] = (short)bf_rne(a1.w);
        Af1[0] = (short)bf_rne(a2.x); Af1[1] = (short)bf_rne(a2.y);
        Af1[2] = (short)bf_rne(a2.z); Af1[3] = (short)bf_rne(a2.w);
        Af1[4] = (short)bf_rne(a3.x); Af1[5] = (short)bf_rne(a3.y);
        Af1[6] = (short)bf_rne(a3.z); Af1[7] = (short)bf_rne(a3.w);
        f4v acc[4] = {{0.f, 0.f, 0.f, 0.f},
                      {0.f, 0.f, 0.f, 0.f},
                      {0.f, 0.f, 0.f, 0.f},
                      {0.f, 0.f, 0.f, 0.f}};
#pragma unroll
        for (int nb = 0; nb < 4; ++nb)
            acc[nb] = __builtin_amdgcn_mfma_f32_16x16x32_bf16(Af0, Bf[0][nb], acc[nb], 0, 0, 0);
#pragma unroll
        for (int nb = 0; nb < 4; ++nb)
            acc[nb] = __builtin_amdgcn_mfma_f32_16x16x32_bf16(Af1, Bf[1][nb], acc[nb], 0, 0, 0);
#pragma unroll
        for (int nb = 0; nb < 4; ++nb)
#pragma unroll
            for (int r = 0; r < 4; ++r) {
                int rowi = gbase + quad * 4 + r;
                if (rowi < N)
                    hout[(size_t)rowi * D + nb * 16 + m] =
                        (u16)bf_rne(acc[nb][r] * ldv[(g << 4) + quad * 4 + r]);
            }
    }
}

// ---------------- dense GEMM via MFMA (layer 2, bf16 input, unscaled) ---------
__global__ __launch_bounds__(256) void gemm_k(const u32* __restrict__ hb,
                                              const float* __restrict__ W,
                                              u16* __restrict__ hout, int N) {
    int t = threadIdx.x;
    int lane = t & 63;
    int m = lane & 15;
    int quad = lane >> 4;
    bf8v Bf[2][4];
    load_B(W, Bf, m, quad);
    int ngroups = (N + 15) >> 4;
    int g = blockIdx.x * 4 + (t >> 6);
    int stride = gridDim.x * 4;
    for (; g < ngroups; g += stride) {
        int base = g * 16;
        int r0 = base + m;
        if (r0 >= N) r0 = N - 1;
        bf8v Af0 = *(const bf8v*)(hb + (size_t)r0 * 32 + quad * 4);
        bf8v Af1 = *(const bf8v*)(hb + (size_t)r0 * 32 + 16 + quad * 4);
        f4v acc[4] = {{0.f, 0.f, 0.f, 0.f},
                      {0.f, 0.f, 0.f, 0.f},
                      {0.f, 0.f, 0.f, 0.f},
                      {0.f, 0.f, 0.f, 0.f}};
#pragma unroll
        for (int nb = 0; nb < 4; ++nb)
            acc[nb] = __builtin_amdgcn_mfma_f32_16x16x32_bf16(Af0, Bf[0][nb], acc[nb], 0, 0, 0);
#pragma unroll
        for (int nb = 0; nb < 4; ++nb)
            acc[nb] = __builtin_amdgcn_mfma_f32_16x16x32_bf16(Af1, Bf[1][nb], acc[nb], 0, 0, 0);
#pragma unroll
        for (int nb = 0; nb < 4; ++nb)
#pragma unroll
            for (int r = 0; r < 4; ++r) {
                int rowi = base + quad * 4 + r;
                if (rowi < N) hout[(size_t)rowi * D + nb * 16 + m] = (u16)bf_rne(acc[nb][r]);
            }
    }
}

// ---------------- edge-driven agg: out = relu(dinv*(self + sum h'[src]) + b) --
// Block per 128-node bucket. acc[128][65] f32 in LDS (33 KB -> 4 blocks/CU).
// 8 lanes per edge (p = lane&7 covers 16 B of the 128 B row); ds_add_f32 into
// acc[dloc]. APAD=65 -> bank = (dloc + 8p + k) % 32: random dloc spreads banks.
// No pr structure, no pads, no chains, no per-edge weights (folded into h').
// Layer 1 (out_b16): stores z = dinv*y so gemm2's output is pre-scaled.
__global__ __launch_bounds__(256) void agge_k(const uint4* __restrict__ h4,
                                              const u32* __restrict__ pairs,
                                              const int* __restrict__ histT,
                                              const int* __restrict__ blockoff2,
                                              const float* __restrict__ dinv,
                                              const float* __restrict__ bias,
                                              float* __restrict__ out_f32,
                                              u16* __restrict__ out_b16,
                                              int N, int nbuck, int E) {
    __shared__ float acc[BUCK * APAD];
    __shared__ float ldv[BUCK];
    int t = threadIdx.x;
    int b = blockIdx.x;
    int base = b << BSHIFT;
    int nvalid = min(BUCK, N - base);
    for (int i = t; i < BUCK * APAD; i += 256) acc[i] = 0.f;
    if (t < nvalid) ldv[t] = dinv[base + t];
    __syncthreads();
    int s0 = seg_at(histT, blockoff2, b * NB);
    int s1 = (b + 1 < nbuck) ? seg_at(histT, blockoff2, (b + 1) * NB) : E;
    int p = t & 7, g = t >> 3;  // 32 edge-groups per block iteration
#pragma unroll 4
    for (int j = s0 + g; j < s1; j += 32) {
        u32 pe = pairs[j];
        u32 srcn = pe & 0x00FFFFFFu;
        int dloc = (int)(pe >> 24);
        uint4 gv = h4[(size_t)srcn * 8 + p];
        float* ap = acc + dloc * APAD + p * 8;
        atomicAdd(ap + 0, bf_lo(gv.x)); atomicAdd(ap + 1, bf_hi(gv.x));
        atomicAdd(ap + 2, bf_lo(gv.y)); atomicAdd(ap + 3, bf_hi(gv.y));
        atomicAdd(ap + 4, bf_lo(gv.z)); atomicAdd(ap + 5, bf_hi(gv.z));
        atomicAdd(ap + 6, bf_lo(gv.w)); atomicAdd(ap + 7, bf_hi(gv.w));
    }
    __syncthreads();
    float4 ba = *(const float4*)(bias + 8 * p);
    float4 bb = *(const float4*)(bias + 8 * p + 4);
    for (int nd = g; nd < nvalid; nd += 32) {
        int n = base + nd;
        uint4 sv = h4[(size_t)n * 8 + p];  // self h' (already dinv-scaled)
        float di = ldv[nd];
        const float* ap = acc + nd * APAD + p * 8;
        float v0 = fmaxf(fmaf(di, ap[0] + bf_lo(sv.x), ba.x), 0.f);
        float v1 = fmaxf(fmaf(di, ap[1] + bf_hi(sv.x), ba.y), 0.f);
        float v2 = fmaxf(fmaf(di, ap[2] + bf_lo(sv.y), ba.z), 0.f);
        float v3 = fmaxf(fmaf(di, ap[3] + bf_hi(sv.y), ba.w), 0.f);
        float v4 = fmaxf(fmaf(di, ap[4] + bf_lo(sv.z), bb.x), 0.f);
        float v5 = fmaxf(fmaf(di, ap[5] + bf_hi(sv.z), bb.y), 0.f);
        float v6 = fmaxf(fmaf(di, ap[6] + bf_lo(sv.w), bb.z), 0.f);
        float v7 = fmaxf(fmaf(di, ap[7] + bf_hi(sv.w), bb.w), 0.f);
        if (out_b16) {
            uint4 o;
            o.x = bf_rne(di * v0) | (bf_rne(di * v1) << 16);
            o.y = bf_rne(di * v2) | (bf_rne(di * v3) << 16);
            o.z = bf_rne(di * v4) | (bf_rne(di * v5) << 16);
            o.w = bf_rne(di * v6) | (bf_rne(di * v7) << 16);
            *(uint4*)(out_b16 + (size_t)n * D + 8 * p) = o;
        } else {
            float* dstp = out_f32 + (size_t)n * D + 8 * p;
            *(float4*)dstp = make_float4(v0, v1, v2, v3);
            *(float4*)(dstp + 4) = make_float4(v4, v5, v6, v7);
        }
    }
}

// ---------------- launch ----------------

extern "C" void kernel_launch(void* const* d_in, const int* in_sizes, int n_in,
                              void* d_out, int out_size, void* d_ws, size_t ws_size,
                              hipStream_t stream) {
    const float* x  = (const float*)d_in[0];
    const int*   ei = (const int*)d_in[1];
    const float* W1 = (const float*)d_in[2];
    const float* b1 = (const float*)d_in[3];
    const float* W2 = (const float*)d_in[4];
    const float* b2 = (const float*)d_in[5];
    float* out = (float*)d_out;

    int N = in_sizes[0] / D;
    int E = in_sizes[1] / 2;
    const int* src = ei;
    const int* dst = ei + E;

    int nbuck = (N + BUCK - 1) >> BSHIFT;  // 782
    int chunk = (E + NB - 1) / NB;
    int M = nbuck * NB;                    // 200192

    char* ws = (char*)d_ws;
    size_t off = 0;
    auto align256 = [](size_t v) { return (v + 255) & ~(size_t)255; };
    float* dinv = (float*)(ws + off);  off += align256((size_t)N * 4);
    int* partials2 = (int*)(ws + off); off += 1024;
    int* blockoff2 = (int*)(ws + off); off += 1024;
    int* donecnt = (int*)(ws + off);   off += 256;
    int* histT = (int*)(ws + off);     off += align256((size_t)M * 4);
    u32* pairs = (u32*)(ws + off);     off += align256((size_t)E * 4);
    u16* h = (u16*)(ws + off);         off += align256((size_t)N * D * 2);
    u16* buf16 = (u16*)(ws + off);     off += align256((size_t)N * D * 2);

    dim3 b256(256);
    int nbG = (M + 1023) / 1024;  // 196
    int ngroups = (N + 15) / 16;
    int gemm_blocks = (ngroups + 3) / 4;

    hist_k<<<NB, b256, 0, stream>>>(dst, histT, E, chunk, nbuck, donecnt);
    gscan1_k<<<nbG, 1024, 0, stream>>>(histT, histT, partials2, blockoff2, donecnt, M);
    bscat_k<<<NB, b256, 0, stream>>>(src, dst, histT, blockoff2, pairs, E, chunk, nbuck);
    // degree->dinv + layer-1 gemm (h = bf16(dinv * (x@W1))), fused per bucket
    bcount_gemm_k<<<nbuck, b256, 0, stream>>>(pairs, histT, blockoff2, dinv, x, W1, h, N,
                                              nbuck, E);
    // layer 1 agg: buf16 = dinv * relu(dinv*(self+sum) + b1)
    agge_k<<<nbuck, b256, 0, stream>>>((const uint4*)h, pairs, histT, blockoff2, dinv, b1,
                                       nullptr, buf16, N, nbuck, E);
    // layer 2: h = buf16 @ W2 (pre-scaled input) ; out = relu(dinv*(self+sum)+b2)
    gemm_k<<<gemm_blocks, b256, 0, stream>>>((const u32*)buf16, W2, h, N);
    agge_k<<<nbuck, b256, 0, stream>>>((const uint4*)h, pairs, histT, blockoff2, dinv, b2,
                                       out, nullptr, N, nbuck, E);
}

// Round 7
// 194.861 us; speedup vs baseline: 5.1220x; 5.1220x over previous
//
#include <hip/hip_runtime.h>

#define D 64
#define NB 256      // partition blocks for hist/scatter
#define BSHIFT 7    // bucket = 128 nodes
#define BUCK (1 << BSHIFT)
#define SLOTS 16    // u32 slots per node: 0=self, 1..14 edges, 15 chain/pad
#define NOVF 256    // sharded chain allocators (R2 lesson: single counter = 75us)
#define CPER 272    // chain blocks per shard
#define MAXCONT (NOVF * CPER)

typedef unsigned int u32;
typedef unsigned short u16;
typedef short bf8v __attribute__((ext_vector_type(8)));
typedef float f4v __attribute__((ext_vector_type(4)));

__device__ __forceinline__ float bf_lo(u32 p) { return __uint_as_float(p << 16); }
__device__ __forceinline__ float bf_hi(u32 p) { return __uint_as_float(p & 0xffff0000u); }
__device__ __forceinline__ u32 bf_rne(float f) {
    u32 u = __float_as_uint(f);
    return (u + 0x7fffu + ((u >> 16) & 1u)) >> 16;
}

// ---------------- pass A: per-block bucket histogram (LDS atomics only) --------
// block 0 zeroes ovf shards + scan done-counter.
__global__ __launch_bounds__(256) void hist_k(const int* __restrict__ dst,
                                              int* __restrict__ histT, int E, int chunk,
                                              int nbuck, int* __restrict__ ovf,
                                              int* __restrict__ donecnt) {
    __shared__ int hh[1024];
    int t = threadIdx.x;
    if (blockIdx.x == 0) {
        if (t < NOVF) ovf[t] = 0;
        if (t == 0) *donecnt = 0;
    }
    for (int b = t; b < nbuck; b += 256) hh[b] = 0;
    __syncthreads();
    int start = blockIdx.x * chunk;
    int endi = min(E, start + chunk);
    for (int j = start + t; j < endi; j += 256) atomicAdd(&hh[dst[j] >> BSHIFT], 1);
    __syncthreads();
    for (int b = t; b < nbuck; b += 256) histT[b * NB + blockIdx.x] = hh[b];
}

// ---------------- grid scan for histT, final partial-scan folded in ----------
__global__ __launch_bounds__(1024) void gscan1_k(const int* __restrict__ in,
                                                 int* __restrict__ out,
                                                 int* __restrict__ partials,
                                                 int* __restrict__ blockoff,
                                                 int* __restrict__ donecnt, int M) {
    __shared__ int wsum[16];
    __shared__ int ps[256];
    __shared__ int lastflag;
    int t = threadIdx.x, wave = t >> 6, lane = t & 63;
    int i = blockIdx.x * 1024 + t;
    int v = (i < M) ? in[i] : 0;
    int x = v;
#pragma unroll
    for (int off = 1; off < 64; off <<= 1) {
        int y = __shfl_up(x, off, 64);
        if (lane >= off) x += y;
    }
    if (lane == 63) wsum[wave] = x;
    __syncthreads();
    if (wave == 0) {
        int s = (lane < 16) ? wsum[lane] : 0;
#pragma unroll
        for (int off = 1; off < 16; off <<= 1) {
            int y = __shfl_up(s, off, 64);
            if (lane >= off) s += y;
        }
        if (lane < 16) wsum[lane] = s;
    }
    __syncthreads();
    int woff = (wave > 0) ? wsum[wave - 1] : 0;
    if (i < M) out[i] = x + woff - v;
    if (t == 0) {
        partials[blockIdx.x] = wsum[15];
        __threadfence();
        int prev = atomicAdd(donecnt, 1);
        lastflag = (prev == (int)gridDim.x - 1);
    }
    __syncthreads();
    if (lastflag) {
        int nb = gridDim.x;
        if (t < 256) ps[t] = (t < nb) ? partials[t] : 0;
        __syncthreads();
        for (int off = 1; off < 256; off <<= 1) {
            int add = (t < 256 && t >= off) ? ps[t - off] : 0;
            __syncthreads();
            if (t < 256) ps[t] += add;
            __syncthreads();
        }
        if (t < 256) blockoff[t] = ps[t] - ((t < nb) ? partials[t] : 0);
    }
}

// seg(x) = histT[x] + blockoff2[x>>10]
__device__ __forceinline__ int seg_at(const int* __restrict__ histT,
                                      const int* __restrict__ blockoff2, int x) {
    return histT[x] + blockoff2[x >> 10];
}

// ---------------- pass B: scatter edges into bucket-sorted segments ----------
// Packed 4B entries: src in bits 0..23, dst&127 in bits 24..31.
__global__ __launch_bounds__(256) void bscat_k(const int* __restrict__ src,
                                               const int* __restrict__ dst,
                                               const int* __restrict__ histT,
                                               const int* __restrict__ blockoff2,
                                               u32* __restrict__ pairs, int E, int chunk,
                                               int nbuck) {
    __shared__ int sbase[1024];
    __shared__ int rank[1024];
    int t = threadIdx.x;
    for (int b = t; b < nbuck; b += 256) {
        sbase[b] = seg_at(histT, blockoff2, b * NB + blockIdx.x);
        rank[b] = 0;
    }
    __syncthreads();
    int start = blockIdx.x * chunk;
    int endi = min(E, start + chunk);
    for (int j = start + t; j < endi; j += 256) {
        int d = dst[j];
        int b = d >> BSHIFT;
        int pos = sbase[b] + atomicAdd(&rank[b], 1);
        pairs[pos] = (u32)src[j] | ((u32)(d & (BUCK - 1)) << 24);
    }
}

__device__ __forceinline__ void load_B(const float* __restrict__ W, bf8v Bf[2][4], int m,
                                       int quad) {
#pragma unroll
    for (int kc = 0; kc < 2; ++kc)
#pragma unroll
        for (int nb = 0; nb < 4; ++nb)
#pragma unroll
            for (int j = 0; j < 8; ++j)
                Bf[kc][nb][j] = (short)bf_rne(W[(32 * kc + 8 * quad + j) * D + m + 16 * nb]);
}

// ---------------- pass C: count + dinv + slot init + scatter + scaled gemm1 ---
// Weight-free slots (dinv folded into h'): slot holds just a src index.
// 0 = self (n); 1..14 = edge srcs; pads = N (zero row of h'); 15 = pad or
// chain 0x80000000|cb. Chain blocks at pr[(N+c)*16]: 15 payload + link.
// Phase order: count -> dinv -> init (coalesced int4) -> edge scatter (LDS cur)
// -> layer-1 gemm h' = bf16(dinv*(x@W1)) for this bucket's 128 rows.
// Block 0 also zeroes h' row N (the pad target).
__global__ __launch_bounds__(256) void bfill3_k(
    const u32* __restrict__ pairs, const int* __restrict__ histT,
    const int* __restrict__ blockoff2, float* __restrict__ dinv,
    u32* __restrict__ pr, int* __restrict__ ovf,
    const float* __restrict__ xf, const float* __restrict__ W,
    u16* __restrict__ hout, int N, int nbuck, int E) {
    __shared__ int c[BUCK];
    __shared__ int lcur[BUCK];
    __shared__ int lcb[BUCK];
    __shared__ int lnb[BUCK];
    __shared__ float ldv[BUCK];
    int t = threadIdx.x;
    int b = blockIdx.x;
    int base = b << BSHIFT;
    int nvalid = min(BUCK, N - base);
    if (t < BUCK) c[t] = 0;
    if (b == 0 && t < 32) ((u32*)(hout + (size_t)N * D))[t] = 0u;  // zero row
    __syncthreads();
    int s0 = seg_at(histT, blockoff2, b * NB);
    int s1 = (b + 1 < nbuck) ? seg_at(histT, blockoff2, (b + 1) * NB) : E;
    for (int j = s0 + t; j < s1; j += 256) atomicAdd(&c[pairs[j] >> 24], 1);
    __syncthreads();
    if (t < BUCK) {
        int nblk = 0, cb = 0;
        int n = base + t;
        if (t < nvalid) {
            int cc = c[t];
            float di = rsqrtf((float)cc + 1.0f);
            ldv[t] = di;
            dinv[n] = di;
            nblk = (cc > 14) ? (cc / 15) : 0;
            if (nblk) {
                cb = (n & (NOVF - 1)) * CPER + atomicAdd(&ovf[n & (NOVF - 1)], nblk);
                for (int k = 0; k < nblk; ++k) {
                    int4* b4 = (int4*)(pr + ((size_t)N + (size_t)(cb + k)) * SLOTS);
                    int4 pad = make_int4(N, N, N, N);
                    b4[0] = pad; b4[1] = pad; b4[2] = pad;
                    b4[3] = make_int4(N, N, N,
                        (k < nblk - 1) ? (int)(0x80000000u | (u32)(cb + k + 1)) : N);
                }
            }
        }
        lcur[t] = 1;
        lcb[t] = cb;
        lnb[t] = nblk;
    }
    __syncthreads();
    // coalesced main slot-init: nvalid*4 int4s, contiguous
    int4* mb = (int4*)(pr + (size_t)base * SLOTS);
    for (int f = t; f < nvalid * 4; f += 256) {
        int nd = f >> 2, q = f & 3;
        int4 v = make_int4(N, N, N, N);
        if (q == 0) v.x = base + nd;                                     // self
        if (q == 3 && lnb[nd]) v.w = (int)(0x80000000u | (u32)lcb[nd]);  // chain
        mb[f] = v;
    }
    __syncthreads();
    // edge scatter (4B stores)
    for (int j = s0 + t; j < s1; j += 256) {
        u32 pe = pairs[j];
        u32 s = pe & 0x00FFFFFFu;
        int dloc = (int)(pe >> 24);
        int pos = atomicAdd(&lcur[dloc], 1);
        size_t w;
        if (pos < 15)
            w = (size_t)(base + dloc) * SLOTS + pos;
        else {
            int r = pos - 15;
            w = ((size_t)N + (size_t)(lcb[dloc] + r / 15)) * SLOTS + (r % 15);
        }
        pr[w] = s;
    }
    // layer-1 gemm for rows [base, base+BUCK), store scaled by ldv (dinv fold)
    int wave = t >> 6, lanei = t & 63, m = lanei & 15, quad = lanei >> 4;
    bf8v Bf[2][4];
    load_B(W, Bf, m, quad);
    for (int g = wave; g < BUCK / 16; g += 4) {
        int gbase = base + g * 16;
        if (gbase >= N) break;
        int r0 = gbase + m;
        if (r0 >= N) r0 = N - 1;
        const float* rp = xf + (size_t)r0 * D;
        float4 a0 = *(const float4*)(rp + quad * 8);
        float4 a1 = *(const float4*)(rp + quad * 8 + 4);
        float4 a2 = *(const float4*)(rp + 32 + quad * 8);
        float4 a3 = *(const float4*)(rp + 32 + quad * 8 + 4);
        bf8v Af0, Af1;
        Af0[0] = (short)bf_rne(a0.x); Af0[1] = (short)bf_rne(a0.y);
        Af0[2] = (short)bf_rne(a0.z); Af0[3] = (short)bf_rne(a0.w);
        Af0[4] = (short)bf_rne(a1.x); Af0[5] = (short)bf_rne(a1.y);
        Af0[6] = (short)bf_rne(a1.z); Af0[7] = (short)bf_rne(a1.w);
        Af1[0] = (short)bf_rne(a2.x); Af1[1] = (short)bf_rne(a2.y);
        Af1[2] = (short)bf_rne(a2.z); Af1[3] = (short)bf_rne(a2.w);
        Af1[4] = (short)bf_rne(a3.x); Af1[5] = (short)bf_rne(a3.y);
        Af1[6] = (short)bf_rne(a3.z); Af1[7] = (short)bf_rne(a3.w);
        f4v acc[4] = {{0.f, 0.f, 0.f, 0.f},
                      {0.f, 0.f, 0.f, 0.f},
                      {0.f, 0.f, 0.f, 0.f},
                      {0.f, 0.f, 0.f, 0.f}};
#pragma unroll
        for (int nb = 0; nb < 4; ++nb)
            acc[nb] = __builtin_amdgcn_mfma_f32_16x16x32_bf16(Af0, Bf[0][nb], acc[nb], 0, 0, 0);
#pragma unroll
        for (int nb = 0; nb < 4; ++nb)
            acc[nb] = __builtin_amdgcn_mfma_f32_16x16x32_bf16(Af1, Bf[1][nb], acc[nb], 0, 0, 0);
#pragma unroll
        for (int nb = 0; nb < 4; ++nb)
#pragma unroll
            for (int r = 0; r < 4; ++r) {
                int rowi = gbase + quad * 4 + r;
                if (rowi < N)
                    hout[(size_t)rowi * D + nb * 16 + m] =
                        (u16)bf_rne(acc[nb][r] * ldv[(g << 4) + quad * 4 + r]);
            }
    }
}

// ---------------- dense GEMM via MFMA (layer 2, bf16 input, unscaled) ---------
// Also zeroes g' row N (pad target for agg2).
__global__ __launch_bounds__(256) void gemm_k(const u32* __restrict__ hb,
                                              const float* __restrict__ W,
                                              u16* __restrict__ hout, int N) {
    int t = threadIdx.x;
    if (blockIdx.x == 0 && t < 32) ((u32*)(hout + (size_t)N * D))[t] = 0u;
    int lane = t & 63;
    int m = lane & 15;
    int quad = lane >> 4;
    bf8v Bf[2][4];
    load_B(W, Bf, m, quad);
    int ngroups = (N + 15) >> 4;
    int g = blockIdx.x * 4 + (t >> 6);
    int stride = gridDim.x * 4;
    for (; g < ngroups; g += stride) {
        int base = g * 16;
        int r0 = base + m;
        if (r0 >= N) r0 = N - 1;
        bf8v Af0 = *(const bf8v*)(hb + (size_t)r0 * 32 + quad * 4);
        bf8v Af1 = *(const bf8v*)(hb + (size_t)r0 * 32 + 16 + quad * 4);
        f4v acc[4] = {{0.f, 0.f, 0.f, 0.f},
                      {0.f, 0.f, 0.f, 0.f},
                      {0.f, 0.f, 0.f, 0.f},
                      {0.f, 0.f, 0.f, 0.f}};
#pragma unroll
        for (int nb = 0; nb < 4; ++nb)
            acc[nb] = __builtin_amdgcn_mfma_f32_16x16x32_bf16(Af0, Bf[0][nb], acc[nb], 0, 0, 0);
#pragma unroll
        for (int nb = 0; nb < 4; ++nb)
            acc[nb] = __builtin_amdgcn_mfma_f32_16x16x32_bf16(Af1, Bf[1][nb], acc[nb], 0, 0, 0);
#pragma unroll
        for (int nb = 0; nb < 4; ++nb)
#pragma unroll
            for (int r = 0; r < 4; ++r) {
                int rowi = base + quad * 4 + r;
                if (rowi < N) hout[(size_t)rowi * D + nb * 16 + m] = (u16)bf_rne(acc[nb][r]);
            }
    }
}

#define ADD8(gt)                                                    \
    v0 += bf_lo((gt).x); v1 += bf_hi((gt).x);                       \
    v2 += bf_lo((gt).y); v3 += bf_hi((gt).y);                       \
    v4 += bf_lo((gt).z); v5 += bf_hi((gt).z);                       \
    v6 += bf_lo((gt).w); v7 += bf_hi((gt).w);

// ---------------- weight-free gather agg: out = relu(dinv*(sum h'[slot]) + b) -
// R5's proven 2-node/wave structure; slots are bare u32 indices (one int4 per
// lane covers its 4 slots). Pads point at h' row N (zeros, L1-hot). Sign bit
// on slot15 = chain pointer; sanitized to N at gather. Layer 1 stores
// u = dinv*relu(...) so gemm2's output is pre-scaled.
__global__ __launch_bounds__(256) void aggu_k(const uint4* __restrict__ h4,
                                              const u32* __restrict__ pr,
                                              const float* __restrict__ dinv,
                                              const float* __restrict__ bias,
                                              float* __restrict__ out_f32,
                                              u16* __restrict__ out_b16, int N) {
    int t = threadIdx.x;
    int lane = t & 63;
    int p = lane & 7;
    int qh = (lane >> 3) & 3;
    int hh = lane >> 5;
    int fsel = (lane & 32) | 31;  // per-half broadcast src (lane 31 / lane 63)
    float4 ba = *(const float4*)(bias + 8 * p);
    float4 bb = *(const float4*)(bias + 8 * p + 4);
    int npair = (N + 1) >> 1;
    int wid = blockIdx.x * 4 + (t >> 6);
    int nw = gridDim.x * 4;
    if (wid >= npair) return;
    const int4* pr4 = (const int4*)pr;
    int n0 = wid * 2 + hh;
    if (n0 >= N) n0 = N - 1;
    int4 pel = pr4[(size_t)n0 * 4 + qh];
    float pdv = dinv[n0];
    for (int i = wid; i < npair; i += nw) {
        int n = 2 * i + hh;
        if (n >= N) n = N - 1;
        int4 el = pel;
        float di = pdv;
        u32 i0 = ((int)el.x < 0) ? (u32)N : (u32)el.x;
        u32 i1 = ((int)el.y < 0) ? (u32)N : (u32)el.y;
        u32 i2 = ((int)el.z < 0) ? (u32)N : (u32)el.z;
        u32 i3 = ((int)el.w < 0) ? (u32)N : (u32)el.w;
        uint4 g0 = h4[(size_t)i0 * 8 + p];
        uint4 g1 = h4[(size_t)i1 * 8 + p];
        uint4 g2 = h4[(size_t)i2 * 8 + p];
        uint4 g3 = h4[(size_t)i3 * 8 + p];
        {   // prefetch next pair's slot quad + dinv
            int j = i + nw;
            int jn = (j < npair) ? (2 * j + hh) : n;
            if (jn >= N) jn = N - 1;
            pel = pr4[(size_t)jn * 4 + qh];
            pdv = dinv[jn];
        }
        float v0 = 0.f, v1 = 0.f, v2 = 0.f, v3 = 0.f;
        float v4 = 0.f, v5 = 0.f, v6 = 0.f, v7 = 0.f;
        ADD8(g0); ADD8(g1); ADD8(g2); ADD8(g3);
        // chain path (deg > 14): half-uniform; idle half gathers zero row
        int sl15 = __shfl(el.w, fsel, 64);
        while (__any(sl15 < 0)) {
            int4 e;
            if (sl15 < 0) {
                int cc = sl15 & 0x7FFFFFFF;
                const int4* bpc = pr4 + ((size_t)N + (size_t)cc) * 4;
                e = bpc[qh];
            } else {
                e = make_int4(N, N, N, N);  // zero-row no-ops
            }
            u32 j0 = ((int)e.x < 0) ? (u32)N : (u32)e.x;
            u32 j1 = ((int)e.y < 0) ? (u32)N : (u32)e.y;
            u32 j2 = ((int)e.z < 0) ? (u32)N : (u32)e.z;
            u32 j3 = ((int)e.w < 0) ? (u32)N : (u32)e.w;
            g0 = h4[(size_t)j0 * 8 + p];
            g1 = h4[(size_t)j1 * 8 + p];
            g2 = h4[(size_t)j2 * 8 + p];
            g3 = h4[(size_t)j3 * 8 + p];
            ADD8(g0); ADD8(g1); ADD8(g2); ADD8(g3);
            sl15 = __shfl(e.w, fsel, 64);
        }
        // reduce over qh within each 32-lane half
        v0 += __shfl_xor(v0, 8, 64);  v1 += __shfl_xor(v1, 8, 64);
        v2 += __shfl_xor(v2, 8, 64);  v3 += __shfl_xor(v3, 8, 64);
        v4 += __shfl_xor(v4, 8, 64);  v5 += __shfl_xor(v5, 8, 64);
        v6 += __shfl_xor(v6, 8, 64);  v7 += __shfl_xor(v7, 8, 64);
        v0 += __shfl_xor(v0, 16, 64); v1 += __shfl_xor(v1, 16, 64);
        v2 += __shfl_xor(v2, 16, 64); v3 += __shfl_xor(v3, 16, 64);
        v4 += __shfl_xor(v4, 16, 64); v5 += __shfl_xor(v5, 16, 64);
        v6 += __shfl_xor(v6, 16, 64); v7 += __shfl_xor(v7, 16, 64);
        v0 = fmaxf(fmaf(di, v0, ba.x), 0.f); v1 = fmaxf(fmaf(di, v1, ba.y), 0.f);
        v2 = fmaxf(fmaf(di, v2, ba.z), 0.f); v3 = fmaxf(fmaf(di, v3, ba.w), 0.f);
        v4 = fmaxf(fmaf(di, v4, bb.x), 0.f); v5 = fmaxf(fmaf(di, v5, bb.y), 0.f);
        v6 = fmaxf(fmaf(di, v6, bb.z), 0.f); v7 = fmaxf(fmaf(di, v7, bb.w), 0.f);
        if (qh == 0) {
            if (out_b16) {
                uint4 o;
                o.x = bf_rne(di * v0) | (bf_rne(di * v1) << 16);
                o.y = bf_rne(di * v2) | (bf_rne(di * v3) << 16);
                o.z = bf_rne(di * v4) | (bf_rne(di * v5) << 16);
                o.w = bf_rne(di * v6) | (bf_rne(di * v7) << 16);
                *(uint4*)(out_b16 + (size_t)n * D + 8 * p) = o;
            } else {
                float* dstp = out_f32 + (size_t)n * D + 8 * p;
                *(float4*)dstp = make_float4(v0, v1, v2, v3);
                *(float4*)(dstp + 4) = make_float4(v4, v5, v6, v7);
            }
        }
    }
}

// ---------------- launch ----------------

extern "C" void kernel_launch(void* const* d_in, const int* in_sizes, int n_in,
                              void* d_out, int out_size, void* d_ws, size_t ws_size,
                              hipStream_t stream) {
    const float* x  = (const float*)d_in[0];
    const int*   ei = (const int*)d_in[1];
    const float* W1 = (const float*)d_in[2];
    const float* b1 = (const float*)d_in[3];
    const float* W2 = (const float*)d_in[4];
    const float* b2 = (const float*)d_in[5];
    float* out = (float*)d_out;

    int N = in_sizes[0] / D;
    int E = in_sizes[1] / 2;
    const int* src = ei;
    const int* dst = ei + E;

    int nbuck = (N + BUCK - 1) >> BSHIFT;  // 782
    int chunk = (E + NB - 1) / NB;
    int M = nbuck * NB;                    // 200192

    char* ws = (char*)d_ws;
    size_t off = 0;
    auto align256 = [](size_t v) { return (v + 255) & ~(size_t)255; };
    float* dinv = (float*)(ws + off);  off += align256((size_t)N * 4);
    int* partials2 = (int*)(ws + off); off += 1024;
    int* blockoff2 = (int*)(ws + off); off += 1024;
    int* donecnt = (int*)(ws + off);   off += 256;
    int* ovf = (int*)(ws + off);       off += align256(NOVF * 4);
    int* histT = (int*)(ws + off);     off += align256((size_t)M * 4);
    u32* pairs = (u32*)(ws + off);     off += align256((size_t)E * 4);
    u32* pr = (u32*)(ws + off);        off += align256(((size_t)N + MAXCONT) * SLOTS * 4);
    u16* h = (u16*)(ws + off);         off += align256(((size_t)N + 1) * D * 2);
    u16* buf16 = (u16*)(ws + off);     off += align256((size_t)N * D * 2);

    dim3 b256(256);
    int nbG = (M + 1023) / 1024;  // 196
    int ngroups = (N + 15) / 16;
    int gemm_blocks = (ngroups + 3) / 4;

    hist_k<<<NB, b256, 0, stream>>>(dst, histT, E, chunk, nbuck, ovf, donecnt);
    gscan1_k<<<nbG, 1024, 0, stream>>>(histT, histT, partials2, blockoff2, donecnt, M);
    bscat_k<<<NB, b256, 0, stream>>>(src, dst, histT, blockoff2, pairs, E, chunk, nbuck);
    // count + dinv + slot init + scatter + h' = bf16(dinv*(x@W1)), per bucket
    bfill3_k<<<nbuck, b256, 0, stream>>>(pairs, histT, blockoff2, dinv, pr, ovf, x, W1, h,
                                         N, nbuck, E);
    // layer 1 agg: buf16 = dinv * relu(dinv*sum + b1)
    aggu_k<<<2560, b256, 0, stream>>>((const uint4*)h, pr, dinv, b1, nullptr, buf16, N);
    // layer 2: g' = buf16 @ W2 (pre-scaled input); out = relu(dinv*sum + b2)
    gemm_k<<<gemm_blocks, b256, 0, stream>>>((const u32*)buf16, W2, h, N);
    aggu_k<<<2560, b256, 0, stream>>>((const uint4*)h, pr, dinv, b2, out, nullptr, N);
}